// Round 9
// baseline (391.619 us; speedup 1.0000x reference)
//
#include <hip/hip_runtime.h>
#include <stdint.h>

typedef unsigned long long ull;
typedef unsigned int u32;
typedef __attribute__((ext_vector_type(8))) short bf16x8;
typedef __attribute__((ext_vector_type(4))) float f32x4;

// sizes: b=64, f=4, v=256, d=16384, ITERS=10; d-words = 256
//
// ws layout (bytes):
//   in_bits [64][256] ull        @ 0         (131072)
//   est0    [64][4][256] ull     @ 131072    (524288)
//   est1    [64][4][256] ull     @ 655360    (524288)
//   cbw     [4][256][256] ull    @ 1179648   (2097152)  [f][w][v]: bit l = sign cb[f][v][w*64+l]
//   cbT     [4][4][16384] ull    @ 3276800   (2097152)  [f][j][d]: bit l = sign cb[f][j*64+l][d]
//   simAB   [4][64][256] u32     @ 5373952   (262144)   mode0: sh_bf16 | sl_bf16<<16 ; mode1: raw q16
//   bar     [64] ull             @ 5636096   (512)      hand-rolled grid barrier counters
//
// bit = 1 <=> value == -1; product of bipolars = XOR.
// signed split: sim = 16384-2h = 256*sh + sl (sh in [-64,64], sl in [0,255], both bf16-exact)
// est bit = ( sum_v sim[v]*cb[v,d] < 0 )
//
// Cross-XCD data (est*, simAB) uses AGENT-scope atomics: stores write through to MALL,
// loads bypass L2 -> no fences/flushes needed; barriers are atomicAdd + relaxed spin.

#define AS __HIP_MEMORY_SCOPE_AGENT
__device__ __forceinline__ ull ald(const ull* p) {
    return __hip_atomic_load(p, __ATOMIC_RELAXED, AS);
}
__device__ __forceinline__ void ast(ull* p, ull v) {
    __hip_atomic_store(p, v, __ATOMIC_RELAXED, AS);
}
__device__ __forceinline__ u32 ald32(const u32* p) {
    return __hip_atomic_load(p, __ATOMIC_RELAXED, AS);
}
__device__ __forceinline__ void ast32(u32* p, u32 v) {
    __hip_atomic_store(p, v, __ATOMIC_RELAXED, AS);
}

// ---- setup: pack input + init_estimates + codebook in ONE dispatch, 16 words/wave ----
__global__ __launch_bounds__(1024) void pack_mega(
        const float* __restrict__ in, const float* __restrict__ est_f,
        const float* __restrict__ cb,
        ull* __restrict__ in_bits, ull* __restrict__ est_bits, ull* __restrict__ cbw,
        ull* __restrict__ bar) {
    if (blockIdx.x == 0 && threadIdx.x < 64) bar[threadIdx.x] = 0;   // re-zero barriers every launch
    int wid  = (int)((blockIdx.x * 1024 + threadIdx.x) >> 6);   // 21504 waves
    int lane = threadIdx.x & 63;
    int w0 = wid * 16;
    const float* s;
    int wloc;
    if (w0 < 16384)      { s = in;    wloc = w0; }
    else if (w0 < 81920) { s = est_f; wloc = w0 - 16384; }
    else                 { s = cb;    wloc = w0 - 81920; }
    ull ball[16];
    #pragma unroll
    for (int k = 0; k < 16; ++k) {
        float x = s[(size_t)(wloc + k) * 64 + lane];
        ball[k] = __ballot(x < 0.0f);
    }
    if (lane == 0) {
        if (w0 < 16384) {
            #pragma unroll
            for (int k = 0; k < 16; ++k) in_bits[wloc + k] = ball[k];
        } else if (w0 < 81920) {
            #pragma unroll
            for (int k = 0; k < 16; ++k) est_bits[wloc + k] = ball[k];
        } else {
            #pragma unroll
            for (int k = 0; k < 16; ++k) {
                int g = wloc + k;             // (f*256+v)*256 + w
                int f = g >> 16, v = (g >> 8) & 255, w = g & 255;
                cbw[(size_t)(f * 256 + w) * 256 + v] = ball[k];
            }
        }
    }
}

// 16 d per wave: 1 load + 16 ballots + 16 stores
__global__ __launch_bounds__(1024) void pack_cbT(const ull* __restrict__ cbw, ull* __restrict__ cbT) {
    int wid  = (int)((blockIdx.x * 1024 + threadIdx.x) >> 6);   // 16384 waves
    int lane = threadIdx.x & 63;
    int f = wid >> 12, j = (wid >> 10) & 3, w = (wid >> 2) & 255, s2 = wid & 3;
    ull cw = cbw[(size_t)(f * 256 + w) * 256 + j * 64 + lane];
    ull ball[16];
    #pragma unroll
    for (int k = 0; k < 16; ++k)
        ball[k] = __ballot((cw >> (s2 * 16 + k)) & 1ull);
    if (lane == 0) {
        #pragma unroll
        for (int k = 0; k < 16; ++k)
            cbT[(size_t)(f * 4 + j) * 16384 + w * 64 + s2 * 16 + k] = ball[k];
    }
}

// ONE persistent kernel: 10 x (phaseA -> bar -> phaseB -> bar) + final-sim -> bar -> argmax+unpack.
// 256 blocks x 512 threads, 1 block/CU (140KB LDS). XCD-swizzled roles as in the 2-kernel version.
__global__ __launch_bounds__(512) void reso_kernel(
        const ull* __restrict__ in_bits, ull* __restrict__ est0, ull* __restrict__ est1,
        const ull* __restrict__ cbw, const ull* __restrict__ cbT,
        u32* __restrict__ simAB, ull* __restrict__ bar, float* __restrict__ out) {
    __shared__ __align__(16) char smraw[143360];
    ull  (*s_cw)[64]     = (ull (*)[64])smraw;                 //      0..131071  (phase A)
    ull  (*s_ne)[256]    = (ull (*)[256])(smraw + 131072);     // 131072..139263  (phase A)
    short (*s_p)[8][64]  = (short (*)[8][64])(smraw + 139264); // 139264..143359  (phase A)
    int4* sB             = (int4*)smraw;                       //      0..131071  (phase B)
    ull  (*s_ball)[8][4] = (ull (*)[8][4])(smraw + 131072);    // 131072..133119  (phase B)

    int t = threadIdx.x, lane = t & 63, wave = t >> 6;
    int bid = blockIdx.x;
    int f    = (bid & 7) >> 1;                    // XCD-swizzled: each XCD owns one f
    int sub  = (bid & 1) * 32 + (bid >> 3);       // 0..63
    int vblk = sub & 3, bblk = sub >> 2;          // A-role: 4 vblk x 16 bblk
    int dblk = sub;                               // B-role: 64 dblk

    // prologue: stage s_cw (256w x 64v slice) for iteration 0
    #pragma unroll 4
    for (int i = 0; i < 16; ++i) {
        int idx = i * 1024 + t * 2;
        int w = idx >> 6, v = idx & 63;
        *(ulonglong2*)&s_cw[w][v] =
            *(const ulonglong2*)&cbw[(size_t)(f * 256 + w) * 256 + vblk * 64 + v];
    }

    for (int itr = 0; itr <= 10; ++itr) {
        ull* estIn  = (itr & 1) ? est1 : est0;
        ull* estOut = (itr & 1) ? est0 : est1;
        const int mode = (itr == 10);

        // ================= phase A: popcount sim =================
        #pragma unroll
        for (int i = 0; i < 2; ++i) {
            int idx = i * 512 + t;
            int bl = idx >> 8, w = idx & 255;
            int b = bblk * 4 + bl;
            ull e0 = ald(&estIn[(size_t)(b * 4 + 0) * 256 + w]);
            ull e1 = ald(&estIn[(size_t)(b * 4 + 1) * 256 + w]);
            ull e2 = ald(&estIn[(size_t)(b * 4 + 2) * 256 + w]);
            ull e3 = ald(&estIn[(size_t)(b * 4 + 3) * 256 + w]);
            ull ef = (f == 0) ? e0 : ((f == 1) ? e1 : ((f == 2) ? e2 : e3));
            s_ne[bl][w] = mode ? ef : (in_bits[(size_t)b * 256 + w] ^ e0 ^ e1 ^ e2 ^ e3 ^ ef);
        }
        __syncthreads();
        {   // wave = 32-w chunk; lane = v-local; accumulate all 4 b rows per cb read
            int acc0 = 0, acc1 = 0, acc2 = 0, acc3 = 0;
            #pragma unroll 8
            for (int w = wave * 32; w < wave * 32 + 32; ++w) {
                ull cwv = s_cw[w][lane];
                acc0 += __popcll(s_ne[0][w] ^ cwv);
                acc1 += __popcll(s_ne[1][w] ^ cwv);
                acc2 += __popcll(s_ne[2][w] ^ cwv);
                acc3 += __popcll(s_ne[3][w] ^ cwv);
            }
            s_p[0][wave][lane] = (short)acc0;
            s_p[1][wave][lane] = (short)acc1;
            s_p[2][wave][lane] = (short)acc2;
            s_p[3][wave][lane] = (short)acc3;
        }
        __syncthreads();
        if (t < 256) {
            int bi = t >> 6, v2 = t & 63;
            int h = 0;
            #pragma unroll
            for (int c = 0; c < 8; ++c) h += s_p[bi][c][v2];
            int b = bblk * 4 + bi, v = vblk * 64 + v2;
            u32 val;
            if (!mode) {
                int sim = 16384 - 2 * h;          // [-16384, 16384]
                int sh = sim >> 8, sl = sim & 255; // sim = 256*sh + sl exactly
                val = (u32)(__float_as_uint((float)sh) >> 16)
                    | ((u32)(__float_as_uint((float)sl) >> 16) << 16);
            } else {
                val = (u32)(16384 - h);           // raw q16 for argmax
            }
            ast32(&simAB[((size_t)(f * 64 + b) << 8) + v], val);
        }
        __syncthreads();                           // drains vmcnt: stores are MALL-visible
        if (t == 0) atomicAdd(&bar[itr * 2], 1ull);
        if (!mode) {
            // overlap barrier wait: stage sB (codebook bits -> bf16 B-frags), no phase-A dep
            #pragma unroll 4
            for (int it2 = 0; it2 < 16; ++it2) {
                int flat = it2 * 512 + t;         // 8 kc * 16 nt * 64 lanes
                int kc = flat >> 10, nt = (flat >> 6) & 15, l = flat & 63;
                int v0 = kc * 32 + ((l >> 4) << 3);
                int d  = dblk * 256 + nt * 16 + (l & 15);
                ull w = cbT[((size_t)f * 4 + (v0 >> 6)) * 16384 + d];
                unsigned bits = (unsigned)(w >> (v0 & 63)) & 0xFFu;
                int4 valB;
                valB.x = 0x3F803F80 | ((bits & 1u) << 15)        | ((bits & 2u) << 30);
                valB.y = 0x3F803F80 | (((bits >> 2) & 1u) << 15) | (((bits >> 2) & 2u) << 30);
                valB.z = 0x3F803F80 | (((bits >> 4) & 1u) << 15) | (((bits >> 4) & 2u) << 30);
                valB.w = 0x3F803F80 | (((bits >> 6) & 1u) << 15) | (((bits >> 6) & 2u) << 30);
                sB[flat] = valB;
            }
        }
        if (t == 0) { while (ald(&bar[itr * 2]) < 256ull) __builtin_amdgcn_s_sleep(1); }
        __syncthreads();                           // release block; orders sB for MFMA reads
        if (mode) break;

        // ================= phase B: est = sign(GEMM) via MFMA =================
        int mw = wave & 3, ntb = (wave >> 2) << 3;
        const ull* ab = (const ull*)(simAB + (((size_t)(f * 64 + mw * 16 + (lane & 15))) << 8))
                        + ((lane >> 4) << 2);
        bf16x8 Ahi[8], Alo[8];
        #pragma unroll
        for (int kc = 0; kc < 8; ++kc) {
            union { u32 u[4]; bf16x8 v; } H, L;
            #pragma unroll
            for (int p2 = 0; p2 < 4; ++p2) {
                ull w = ald(ab + kc * 16 + p2);   // 2 v per ull: (sh|sl<<16) pairs
                H.u[p2] = (u32)(w & 0xFFFFull) | (((u32)(w >> 32) & 0xFFFFu) << 16);
                L.u[p2] = ((u32)(w >> 16) & 0xFFFFu) | ((u32)(w >> 48) << 16);
            }
            Ahi[kc] = H.v; Alo[kc] = L.v;
        }
        #pragma unroll 2
        for (int ntl = 0; ntl < 8; ++ntl) {
            int nt = ntb + ntl;
            f32x4 acch = {0.f, 0.f, 0.f, 0.f}, accl = {0.f, 0.f, 0.f, 0.f};
            #pragma unroll
            for (int kc = 0; kc < 8; ++kc) {
                bf16x8 B = *(const bf16x8*)&sB[(kc * 16 + nt) * 64 + lane];
                acch = __builtin_amdgcn_mfma_f32_16x16x32_bf16(Ahi[kc], B, acch, 0, 0, 0);
                accl = __builtin_amdgcn_mfma_f32_16x16x32_bf16(Alo[kc], B, accl, 0, 0, 0);
            }
            #pragma unroll
            for (int r = 0; r < 4; ++r) {
                float S = 256.0f * acch[r] + accl[r];   // exact int, |S| < 2^23
                ull m = __ballot(S < 0.0f);
                if (lane == 0) s_ball[wave][nt & 7][r] = m;
            }
        }
        __syncthreads();
        if (t < 256) {
            int b = t >> 2, w4 = t & 3;
            int wv = (b >> 4) + ((w4 >= 2) ? 4 : 0);
            ull word = 0;
            #pragma unroll
            for (int k = 0; k < 4; ++k) {
                int nt = w4 * 4 + k;
                ull m = s_ball[wv][nt & 7][b & 3];
                word |= ((m >> (((b >> 2) & 3) * 16)) & 0xFFFFull) << (k * 16);
            }
            ast(&estOut[((size_t)(b * 4 + f)) * 256 + dblk * 4 + w4], word);
        }
        __syncthreads();                           // drains vmcnt: est stores MALL-visible
        if (t == 0) atomicAdd(&bar[itr * 2 + 1], 1ull);
        // overlap barrier wait: stage s_cw for next phase A (no est dep)
        #pragma unroll 4
        for (int i = 0; i < 16; ++i) {
            int idx = i * 1024 + t * 2;
            int w = idx >> 6, v = idx & 63;
            *(ulonglong2*)&s_cw[w][v] =
                *(const ulonglong2*)&cbw[(size_t)(f * 256 + w) * 256 + vblk * 64 + v];
        }
        if (t == 0) { while (ald(&bar[itr * 2 + 1]) < 256ull) __builtin_amdgcn_s_sleep(1); }
        __syncthreads();
    }

    // ================= final: argmax|sim| + unpack est =================
    if (t < 64) {
        int b2 = bid >> 2, f2 = bid & 3;
        const ull* sf = (const ull*)(simAB + ((size_t)(f2 * 64 + b2) << 8)) + t * 2;
        ull w0 = ald(sf), w1 = ald(sf + 1);
        int qv[4] = { (int)(u32)w0, (int)(u32)(w0 >> 32),
                      (int)(u32)w1, (int)(u32)(w1 >> 32) };
        int best_a = -1, best_v = 0;
        #pragma unroll
        for (int k = 0; k < 4; ++k) {
            int sim = 2 * qv[k] - 16384;
            int a = sim < 0 ? -sim : sim;
            if (a > best_a) { best_a = a; best_v = t * 4 + k; }   // strict > keeps first index
        }
        #pragma unroll
        for (int off = 1; off < 64; off <<= 1) {
            int oa = __shfl_xor(best_a, off);
            int ov = __shfl_xor(best_v, off);
            if (oa > best_a || (oa == best_a && ov < best_v)) { best_a = oa; best_v = ov; }
        }
        if (t == 0) out[4194304 + b2 * 4 + f2] = (float)best_v;
    }
    {   // unpack est0 -> +-1.0f: 256 blocks x 512 threads x 32 floats
        int widx = bid * 256 + (t >> 1);
        ull w = ald(&est0[widx]);
        u32 bits = (u32)(w >> ((t & 1) * 32));
        int base = bid * 16384 + (t >> 1) * 64 + (t & 1) * 32;
        #pragma unroll
        for (int j = 0; j < 8; ++j) {
            float4 o;
            o.x = ((bits >> (j * 4 + 0)) & 1u) ? -1.0f : 1.0f;
            o.y = ((bits >> (j * 4 + 1)) & 1u) ? -1.0f : 1.0f;
            o.z = ((bits >> (j * 4 + 2)) & 1u) ? -1.0f : 1.0f;
            o.w = ((bits >> (j * 4 + 3)) & 1u) ? -1.0f : 1.0f;
            *(float4*)(out + base + j * 4) = o;
        }
    }
}

extern "C" void kernel_launch(void* const* d_in, const int* in_sizes, int n_in,
                              void* d_out, int out_size, void* d_ws, size_t ws_size,
                              hipStream_t stream) {
    const float* input    = (const float*)d_in[0];
    const float* init_est = (const float*)d_in[1];
    const float* cb       = (const float*)d_in[2];
    float* out = (float*)d_out;
    char* ws = (char*)d_ws;

    ull* in_bits = (ull*)(ws + 0);
    ull* est0    = (ull*)(ws + 131072);
    ull* est1    = (ull*)(ws + 655360);
    ull* cbw     = (ull*)(ws + 1179648);
    ull* cbT     = (ull*)(ws + 3276800);
    u32* simAB   = (u32*)(ws + 5373952);
    ull* bar     = (ull*)(ws + 5636096);

    pack_mega<<<1344, 1024, 0, stream>>>(input, init_est, cb, in_bits, est0, cbw, bar);
    pack_cbT<<<1024, 1024, 0, stream>>>(cbw, cbT);

    void* kargs[] = {
        (void*)&in_bits, (void*)&est0, (void*)&est1, (void*)&cbw, (void*)&cbT,
        (void*)&simAB, (void*)&bar, (void*)&out
    };
    hipLaunchCooperativeKernel(reinterpret_cast<void*>(reso_kernel),
                               dim3(256, 1, 1), dim3(512, 1, 1), kargs, 0, stream);
}